// Round 13
// baseline (584.899 us; speedup 1.0000x reference)
//
#include <hip/hip_runtime.h>
#include <hip/hip_bf16.h>
#include <math.h>

// Problem constants (B=2048, D=512, C=100000)
constexpr int Bq = 2048;
constexpr int Dq = 512;
constexpr int Cq = 100000;
constexpr int NPAD = 100096;     // 782 * 128

constexpr float SCALE = 64.0f;
constexpr float COS_M = 0.8775825618903728f;   // cos(0.5)
constexpr float SIN_M = 0.479425538604203f;    // sin(0.5)
constexpr float THR   = -0.8775825618903728f;  // cos(pi - 0.5)
constexpr float MM    = 0.2397127693021015f;   // sin(pi - 0.5) * 0.5

typedef __attribute__((ext_vector_type(8))) __bf16 bf16x8;
typedef __attribute__((ext_vector_type(4))) float f32x4;

typedef const __attribute__((address_space(1))) unsigned int guint;
typedef __attribute__((address_space(3))) unsigned int suint;

__device__ __forceinline__ void gload_lds16(const unsigned short* g, unsigned short* lds)
{
    __builtin_amdgcn_global_load_lds((guint*)g, (suint*)lds, 16, 0, 0);
}

__device__ __forceinline__ unsigned int pack_bf16x2(float lo, float hi)
{
    __hip_bfloat16 h0 = __float2bfloat16(lo);
    __hip_bfloat16 h1 = __float2bfloat16(hi);
    return ((unsigned int)(*(unsigned short*)&h1) << 16) |
           (unsigned int)(*(unsigned short*)&h0);
}

// ---------------------------------------------------------------------------
// Row L2-normalize fp32 [*][512] -> bf16, wave-per-row, float4 loads,
// pure shuffle reduce. 4 rows per 256-thread block. Pad rows write zeros.
// ---------------------------------------------------------------------------
__global__ __launch_bounds__(256) void normalize_rows_kernel(
    const float* __restrict__ in, unsigned short* __restrict__ out, int nrows)
{
    const int w = threadIdx.x >> 6, lane = threadIdx.x & 63;
    const int row = blockIdx.x * 4 + w;
    float4 a = {0.f, 0.f, 0.f, 0.f}, b = a;
    if (row < nrows) {
        const float4* src = reinterpret_cast<const float4*>(in + (size_t)row * Dq);
        a = src[lane];
        b = src[lane + 64];
    }
    float ss = a.x * a.x + a.y * a.y + a.z * a.z + a.w * a.w
             + b.x * b.x + b.y * b.y + b.z * b.z + b.w * b.w;
    #pragma unroll
    for (int off = 32; off > 0; off >>= 1) ss += __shfl_down(ss, off);
    ss = __shfl(ss, 0);
    const float invn = 1.0f / fmaxf(sqrtf(ss), 1e-12f);

    uint2* out64 = reinterpret_cast<uint2*>(out + (size_t)row * Dq);
    uint2 pa, pb;
    pa.x = pack_bf16x2(a.x * invn, a.y * invn);
    pa.y = pack_bf16x2(a.z * invn, a.w * invn);
    pb.x = pack_bf16x2(b.x * invn, b.y * invn);
    pb.y = pack_bf16x2(b.z * invn, b.w * invn);
    out64[lane] = pa;
    out64[lane + 64] = pb;
}

// ---------------------------------------------------------------------------
// 128x128 GEMM, BK=64, 8 kt, 4 waves (2M x 2N, 64x64 per wave).
// ROUND 13: B (classes) comes DIRECT FROM L2 into registers — no LDS staging,
// no ds_read for B. Lane's B fragment is 16 contiguous bytes of a Bn row
// (class = n0+wc+ni*16+fr, elems kt*64+ks*32+kg*8), loaded as dwordx4 with a
// 1-kt register prefetch (bA/bB double buffer). B-strip is L2-resident (T1
// swizzle: 16 consecutive bids share tn). LDS holds only A: 2 x 16KB dbuf,
// per-kt LDS traffic halves (8 ds_reads/wave + 16KB stage vs 16 + 32KB).
//
// Pipeline per kt: read A-frags (8 b128); lgkm(0); barrier;
//   stage A(kt+2) -> same-parity buffer (4 issues); load B(kt+1) -> regs (8);
//   32 MFMA (setprio, compiler auto-waits B(kt) regs);
//   gate vmcnt(12) [kt<6: leaves A(kt+2)x4 + B(kt+1)x8 in flight -> A(kt+1)
//   landed] / vmcnt(8) [kt==6] / none [kt==7]; barrier.
// Prologue: A(0),A(1) staged, B(0) loaded; vmcnt(12) -> A(0) landed.
// T1 XCD swizzle, T2 involution swizzle on A, T5 setprio, swapped-operand
// MFMA, R12's validated two-pass [64][132] line-aligned nt epilogue.
// LDS 33792 B; VGPR ~185 (acc 64 + B dbuf 64) -> (256,2), 2 blocks/CU.
// ---------------------------------------------------------------------------
__global__ __launch_bounds__(256, 2) void arc_gemm_kernel(
    const unsigned short* __restrict__ A,
    const unsigned short* __restrict__ Bn,
    const int* __restrict__ labels,
    float* __restrict__ out)
{
    extern __shared__ unsigned short lds[];   // 33792 B

    // T1: XCD-aware bijective swizzle (12512 = 8 * 1564 exact)
    const int cpx = (int)gridDim.x >> 3;
    const int bid = ((int)blockIdx.x & 7) * cpx + ((int)blockIdx.x >> 3);
    const int tm = bid & 15;         // 16 m-tiles share one B-strip per XCD
    const int tn = bid >> 4;
    const int m0 = tm * 128, n0 = tn * 128;

    const int t = threadIdx.x;
    const int w = t >> 6, lane = t & 63;
    const int wr = (w >> 1) * 64;    // wave M (emb) origin
    const int wc = (w & 1) * 64;     // wave N (class) origin
    const int fr = lane & 15, kg = lane >> 4;
    const int s7 = fr & 7;
    const int c0 = (kg ^ s7) * 8;          // A swizzled chunk, ks=0 (elems)
    const int c1 = ((4 + kg) ^ s7) * 8;    // ks=1

    // A staging: issue s covers rows [s*32, s*32+32); thread t -> row t>>3,
    // source chunk pre-swizzled (involution with the ds_read XOR).
    const int trow = t >> 3;
    const int tch = ((t & 7) ^ (trow & 7)) * 8;
    const unsigned short* gA = A + (size_t)(m0 + trow) * Dq + tch;
    const int dstA = trow * 64 + (t & 7) * 8;   // linear LDS dest

#define STAGE_A(buf, s, kts) gload_lds16(gA + (size_t)(s) * 32 * Dq + (size_t)(kts) * 64, \
                                         &lds[(buf) * 8192 + (s) * 2048 + dstA])
#define BARRIER() do { __builtin_amdgcn_sched_barrier(0); __builtin_amdgcn_s_barrier(); } while (0)

    // B direct-from-L2 per-lane base: class row (n0+wc+fr), k-chunk kg*8.
    const unsigned short* bp0 = Bn + (size_t)(n0 + wc + fr) * Dq + kg * 8;

    f32x4 acc[4][4];
    #pragma unroll
    for (int i = 0; i < 4; ++i)
        #pragma unroll
        for (int j = 0; j < 4; ++j) acc[i][j] = {0.f, 0.f, 0.f, 0.f};

    bf16x8 bA[4][2], bB[4][2];   // B fragment double buffer (registers)

    // Prologue: A(0)->buf0, A(1)->buf1 (4 issues each); B(0)->bA (8 loads)
    STAGE_A(0, 0, 0); STAGE_A(0, 1, 0); STAGE_A(0, 2, 0); STAGE_A(0, 3, 0);
    STAGE_A(1, 0, 1); STAGE_A(1, 1, 1); STAGE_A(1, 2, 1); STAGE_A(1, 3, 1);
    #pragma unroll
    for (int ni = 0; ni < 4; ++ni)
        #pragma unroll
        for (int ks = 0; ks < 2; ++ks)
            bA[ni][ks] = *reinterpret_cast<const bf16x8*>(
                bp0 + (size_t)ni * 16 * Dq + ks * 32);
    asm volatile("s_waitcnt vmcnt(12)" ::: "memory");   // A(0) landed
    __builtin_amdgcn_s_barrier();

    const int arow = (wr + fr) * 64;

    #pragma unroll
    for (int kt = 0; kt < 8; ++kt) {
        const int cbo = (kt & 1) * 8192;
        bf16x8 (&bcur)[4][2] = (kt & 1) ? bB : bA;
        bf16x8 (&bnxt)[4][2] = (kt & 1) ? bA : bB;
        bf16x8 afr[4][2];
        #pragma unroll
        for (int mi = 0; mi < 4; ++mi) {
            afr[mi][0] = *reinterpret_cast<const bf16x8*>(&lds[cbo + arow + mi * 1024 + c0]);
            afr[mi][1] = *reinterpret_cast<const bf16x8*>(&lds[cbo + arow + mi * 1024 + c1]);
        }
        asm volatile("s_waitcnt lgkmcnt(0)" ::: "memory");  // frags in regs
        BARRIER();                                          // all waves done with cb
        if (kt < 6) {   // restage same-parity buffer with A(kt+2)
            STAGE_A(kt & 1, 0, kt + 2); STAGE_A(kt & 1, 1, kt + 2);
            STAGE_A(kt & 1, 2, kt + 2); STAGE_A(kt & 1, 3, kt + 2);
        }
        if (kt < 7) {   // prefetch B(kt+1) into the other register buffer
            #pragma unroll
            for (int ni = 0; ni < 4; ++ni)
                #pragma unroll
                for (int ks = 0; ks < 2; ++ks)
                    bnxt[ni][ks] = *reinterpret_cast<const bf16x8*>(
                        bp0 + (size_t)ni * 16 * Dq + (kt + 1) * 64 + ks * 32);
        }
        __builtin_amdgcn_s_setprio(1);
        #pragma unroll
        for (int mi = 0; mi < 4; ++mi)
            #pragma unroll
            for (int ni = 0; ni < 4; ++ni)
                #pragma unroll
                for (int ks = 0; ks < 2; ++ks)
                    acc[mi][ni] = __builtin_amdgcn_mfma_f32_16x16x32_bf16(
                        bcur[ni][ks], afr[mi][ks], acc[mi][ni], 0, 0, 0);
        __builtin_amdgcn_s_setprio(0);
        if (kt < 6)       asm volatile("s_waitcnt vmcnt(12)" ::: "memory"); // A(kt+1) landed
        else if (kt == 6) asm volatile("s_waitcnt vmcnt(8)"  ::: "memory"); // A(7) landed
        BARRIER();
    }

    // ---- Epilogue (R12, validated): two passes of [64][132] f32 overlay ->
    // line-aligned nt stores (8 rows x 512B per instruction).
    // acc mapping: emb row = wr + mi*16 + fr, class col = wc + ni*16 + kg*4 + reg.
    float* lf = reinterpret_cast<float*>(lds);
    #pragma unroll
    for (int pass = 0; pass < 2; ++pass) {
        if ((w >> 1) == pass) {   // waves owning rows [pass*64, pass*64+64)
            #pragma unroll
            for (int mi = 0; mi < 4; ++mi) {
                const int lrow = mi * 16 + fr;            // 0..63
                const int lab = labels[m0 + pass * 64 + lrow];
                #pragma unroll
                for (int ni = 0; ni < 4; ++ni) {
                    const int col0 = wc + ni * 16 + kg * 4;
                    const int gcol0 = n0 + col0;
                    f32x4 v = acc[mi][ni];
                    #pragma unroll
                    for (int r = 0; r < 4; ++r) {
                        if (gcol0 + r == lab) {
                            float c = v[r];
                            float sine = sqrtf(fmaxf(1.0f - c * c, 0.0f));
                            float phi = c * COS_M - sine * SIN_M;
                            v[r] = (c > THR) ? phi : (c - MM);
                        }
                    }
                    v *= SCALE;
                    *reinterpret_cast<f32x4*>(&lf[lrow * 132 + col0]) = v;
                }
            }
        }
        __syncthreads();
        // read back: each instruction = 8 rows x (32 lanes x 16B = 512B/row)
        const int cc = t & 31, rh = t >> 5;   // rh 0..7
        #pragma unroll
        for (int s = 0; s < 8; ++s) {
            const int lrow = s * 8 + rh;
            f32x4 v = *reinterpret_cast<const f32x4*>(&lf[lrow * 132 + cc * 4]);
            const int gcol0 = n0 + cc * 4;
            if (gcol0 < Cq)
                __builtin_nontemporal_store(
                    v, reinterpret_cast<f32x4*>(
                        out + (size_t)(m0 + pass * 64 + lrow) * Cq + gcol0));
        }
        __syncthreads();   // reads done before next pass overwrites lf
    }
#undef STAGE_A
#undef BARRIER
}

extern "C" void kernel_launch(void* const* d_in, const int* in_sizes, int n_in,
                              void* d_out, int out_size, void* d_ws, size_t ws_size,
                              hipStream_t stream)
{
    const float* emb    = (const float*)d_in[0];
    const int*   labels = (const int*)d_in[1];
    const float* weight = (const float*)d_in[2];
    float* out = (float*)d_out;

    unsigned short* Abf = (unsigned short*)d_ws;             // 2 MB
    unsigned short* Bbf = Abf + (size_t)Bq * Dq;             // 102.5 MB

    normalize_rows_kernel<<<Bq / 4, 256, 0, stream>>>(emb, Abf, Bq);
    normalize_rows_kernel<<<NPAD / 4, 256, 0, stream>>>(weight, Bbf, Cq);
    arc_gemm_kernel<<<16 * (NPAD / 128), 256, 33792, stream>>>(Abf, Bbf, labels, out);
}

// Round 15
// 327.964 us; speedup vs baseline: 1.7834x; 1.7834x over previous
//
#include <hip/hip_runtime.h>
#include <hip/hip_bf16.h>
#include <math.h>

// Problem constants (B=2048, D=512, C=100000)
constexpr int Bq = 2048;
constexpr int Dq = 512;
constexpr int Cq = 100000;
constexpr int NPAD = 100096;     // 391 * 256

constexpr float SCALE = 64.0f;
constexpr float COS_M = 0.8775825618903728f;   // cos(0.5)
constexpr float SIN_M = 0.479425538604203f;    // sin(0.5)
constexpr float THR   = -0.8775825618903728f;  // cos(pi - 0.5)
constexpr float MM    = 0.2397127693021015f;   // sin(pi - 0.5) * 0.5

typedef __attribute__((ext_vector_type(8))) __bf16 bf16x8;
typedef __attribute__((ext_vector_type(4))) float f32x4;

typedef const __attribute__((address_space(1))) unsigned int guint;
typedef __attribute__((address_space(3))) unsigned int suint;

__device__ __forceinline__ void gload_lds16(const unsigned short* g, unsigned short* lds)
{
    __builtin_amdgcn_global_load_lds((guint*)g, (suint*)lds, 16, 0, 0);
}

__device__ __forceinline__ unsigned int pack_bf16x2(float lo, float hi)
{
    __hip_bfloat16 h0 = __float2bfloat16(lo);
    __hip_bfloat16 h1 = __float2bfloat16(hi);
    return ((unsigned int)(*(unsigned short*)&h1) << 16) |
           (unsigned int)(*(unsigned short*)&h0);
}

// ---------------------------------------------------------------------------
// Row L2-normalize fp32 [*][512] -> bf16, wave-per-row, float4 loads,
// pure shuffle reduce. 4 rows per 256-thread block. Pad rows write zeros.
// ---------------------------------------------------------------------------
__global__ __launch_bounds__(256) void normalize_rows_kernel(
    const float* __restrict__ in, unsigned short* __restrict__ out, int nrows)
{
    const int w = threadIdx.x >> 6, lane = threadIdx.x & 63;
    const int row = blockIdx.x * 4 + w;
    float4 a = {0.f, 0.f, 0.f, 0.f}, b = a;
    if (row < nrows) {
        const float4* src = reinterpret_cast<const float4*>(in + (size_t)row * Dq);
        a = src[lane];
        b = src[lane + 64];
    }
    float ss = a.x * a.x + a.y * a.y + a.z * a.z + a.w * a.w
             + b.x * b.x + b.y * b.y + b.z * b.z + b.w * b.w;
    #pragma unroll
    for (int off = 32; off > 0; off >>= 1) ss += __shfl_down(ss, off);
    ss = __shfl(ss, 0);
    const float invn = 1.0f / fmaxf(sqrtf(ss), 1e-12f);

    uint2* out64 = reinterpret_cast<uint2*>(out + (size_t)row * Dq);
    uint2 pa, pb;
    pa.x = pack_bf16x2(a.x * invn, a.y * invn);
    pa.y = pack_bf16x2(a.z * invn, a.w * invn);
    pb.x = pack_bf16x2(b.x * invn, b.y * invn);
    pb.y = pack_bf16x2(b.z * invn, b.w * invn);
    out64[lane] = pa;
    out64[lane + 64] = pb;
}

// ---------------------------------------------------------------------------
// ROUND 15 (= R14 with the compile fix: sv/obase hoisted above tile 0).
// Two-n-tile pipelined block. Each block owns m-tile tm and the n-tile PAIR
// pn (cols n0..n0+255). Tile 0: R11 K-loop -> acc -> margin+scale -> sv regs,
// acc rezeroed. Tile 1: same K-loop, but tile-0's 16 nt stores are drip-fed
// 2-per-kt at the TOP of each kt (a full kt ~800cyc to drain before the
// vmcnt(6) gate forces retirement; stores are always older than the 8
// in-flight staging loads, so the counted ledger is unchanged).
// This breaks the sibling-synchronized "K-loop burst then store burst"
// pattern that left the write pipe and LDS pipe serialized (R11 ~270us =
// ~125 LDS + ~122 write, near-zero overlap). Tile 1 stores via the proven
// LDS-transposed line-aligned nt epilogue.
// K-loop = R11 verbatim: 128x128, BK=64, 4 waves (2Mx2N), 64KB dbuf,
// 2-phase/kt, counted-vmcnt rotation (race-audited), T1 XCD swizzle,
// T2 involution LDS swizzle, T5 setprio, swapped-operand MFMA.
// Grid 6256 = 16 m-tiles x 391 pairs = 8 x 782 (T1-bijective).
// LDS 67584 -> 2 blocks/CU. VGPR ~230 (acc 64 + sv 64) under the (256,2) cap.
// ---------------------------------------------------------------------------
__global__ __launch_bounds__(256, 2) void arc_gemm_kernel(
    const unsigned short* __restrict__ A,
    const unsigned short* __restrict__ Bn,
    const int* __restrict__ labels,
    float* __restrict__ out)
{
    extern __shared__ unsigned short lds[];   // 67584 B (K-loop uses 65536)

    // T1: XCD-aware bijective swizzle (6256 = 8 * 782 exact)
    const int cpx = (int)gridDim.x >> 3;
    const int bid = ((int)blockIdx.x & 7) * cpx + ((int)blockIdx.x >> 3);
    const int tm = bid & 15;         // 16 consecutive bids share one B pair-strip
    const int pn = bid >> 4;
    const int m0 = tm * 128, n0 = pn * 256;

    const int t = threadIdx.x;
    const int w = t >> 6, lane = t & 63;
    const int wr = (w >> 1) * 64;    // wave M (emb) origin
    const int wc = (w & 1) * 64;     // wave N (class) origin
    const int fr = lane & 15, kg = lane >> 4;
    const int s7 = fr & 7;
    const int c0 = (kg ^ s7) * 8;          // swizzled chunk, ks=0 (elems)
    const int c1 = ((4 + kg) ^ s7) * 8;    // ks=1

    // staging: thread t covers row trow (0..31) of a 32-row slab, swizzled col
    const int trow = t >> 3;
    const int tch = ((t & 7) ^ (trow & 7)) * 8;
    const unsigned short* gA = A + (size_t)(m0 + trow) * Dq + tch;
    const unsigned short* gBt = Bn + (size_t)(n0 + trow) * Dq + tch;  // tile 0
    const int dstA = trow * 64 + (t & 7) * 8;   // linear LDS dest (= tid*16 B)

#define STAGE_A(buf, s, kts) gload_lds16(gA + (size_t)(s) * 32 * Dq + (size_t)(kts) * 64, \
                                         &lds[(buf) * 16384 + (s) * 2048 + dstA])
#define STAGE_B(buf, s, kts) gload_lds16(gBt + (size_t)(s) * 32 * Dq + (size_t)(kts) * 64, \
                                         &lds[(buf) * 16384 + 8192 + (s) * 2048 + dstA])
#define BARRIER() do { __builtin_amdgcn_sched_barrier(0); __builtin_amdgcn_s_barrier(); } while (0)
#define PROLOGUE() do { \
    STAGE_A(0, 0, 0); STAGE_A(0, 1, 0); STAGE_A(0, 2, 0); STAGE_A(0, 3, 0); \
    STAGE_B(0, 0, 0); STAGE_B(0, 1, 0); STAGE_B(0, 2, 0); STAGE_B(0, 3, 0); \
    STAGE_B(1, 0, 1); STAGE_B(1, 1, 1); STAGE_B(1, 2, 1); STAGE_B(1, 3, 1); \
    STAGE_A(1, 0, 1); STAGE_A(1, 2, 1); \
} while (0)

    const int arow = (wr + fr) * 64;
    const int brow = 8192 + (wc + fr) * 64;

#define LDAQ(dst, q) do { \
    dst[0] = *reinterpret_cast<const bf16x8*>(&lds[cbo + arow + (q) * 1024 + c0]); \
    dst[1] = *reinterpret_cast<const bf16x8*>(&lds[cbo + arow + (q) * 1024 + c1]); \
} while (0)
#define LDB() do { \
    _Pragma("unroll") for (int ni = 0; ni < 4; ++ni) { \
        bfr[ni][0] = *reinterpret_cast<const bf16x8*>(&lds[cbo + brow + ni * 1024 + c0]); \
        bfr[ni][1] = *reinterpret_cast<const bf16x8*>(&lds[cbo + brow + ni * 1024 + c1]); } \
} while (0)
// Operands swapped: A-operand = class frag (bfr), B-operand = emb frag.
#define MFMA_PAIR(q0, a0, q1, a1) do { \
    __builtin_amdgcn_s_setprio(1); \
    _Pragma("unroll") for (int ks = 0; ks < 2; ++ks) \
    _Pragma("unroll") for (int ni = 0; ni < 4; ++ni) { \
        acc[(q0)][ni] = __builtin_amdgcn_mfma_f32_16x16x32_bf16( \
            bfr[ni][ks], a0[ks], acc[(q0)][ni], 0, 0, 0); \
        acc[(q1)][ni] = __builtin_amdgcn_mfma_f32_16x16x32_bf16( \
            bfr[ni][ks], a1[ks], acc[(q1)][ni], 0, 0, 0); } \
    __builtin_amdgcn_s_setprio(0); \
} while (0)

// One kt of the race-audited 2-phase rotation (R11). DO_ST=1 additionally
// drip-feeds 2 tile-0 nt stores at the top (oldest VMEM at the gate).
// Tile-0 cols are always < Cq (max 99967), no guard needed.
#define KT_STEP(kt, DO_ST) { \
        const int cb = (kt) & 1, nb = cb ^ 1; \
        const int cbo = cb * 16384; \
        bf16x8 bfr[4][2]; \
        bf16x8 af0[2], af1[2], af2[2], af3[2]; \
        if (DO_ST) { \
            __builtin_nontemporal_store(sv[(kt) >> 1][((kt) & 1) * 2], \
                reinterpret_cast<f32x4*>(obase + (size_t)((kt) >> 1) * 16 * Cq + (((kt) & 1) * 2) * 16)); \
            __builtin_nontemporal_store(sv[(kt) >> 1][((kt) & 1) * 2 + 1], \
                reinterpret_cast<f32x4*>(obase + (size_t)((kt) >> 1) * 16 * Cq + (((kt) & 1) * 2 + 1) * 16)); \
        } \
        LDB(); LDAQ(af0, 0); LDAQ(af1, 1); \
        if ((kt) < 7) { STAGE_A(nb, 1, (kt) + 1); STAGE_A(nb, 3, (kt) + 1); } \
        BARRIER(); \
        MFMA_PAIR(0, af0, 1, af1); \
        BARRIER(); \
        LDAQ(af2, 2); LDAQ(af3, 3); \
        if ((kt) < 6) { \
            STAGE_B(cb, 0, (kt) + 2); STAGE_B(cb, 1, (kt) + 2); \
            STAGE_B(cb, 2, (kt) + 2); STAGE_B(cb, 3, (kt) + 2); \
            STAGE_A(cb, 0, (kt) + 2); STAGE_A(cb, 2, (kt) + 2); \
        } \
        BARRIER(); \
        MFMA_PAIR(2, af2, 3, af3); \
        if ((kt) < 6) asm volatile("s_waitcnt vmcnt(6)" ::: "memory"); \
        else          asm volatile("s_waitcnt vmcnt(0)" ::: "memory"); \
        BARRIER(); \
    }

    f32x4 acc[4][4];
    #pragma unroll
    for (int i = 0; i < 4; ++i)
        #pragma unroll
        for (int j = 0; j < 4; ++j) acc[i][j] = {0.f, 0.f, 0.f, 0.f};

    // Declared here so KT_STEP's dead if(0) branch parses in tile 0.
    f32x4 sv[4][4];
    float* obase = out + (size_t)(m0 + wr + fr) * Cq + n0 + wc + kg * 4;

    // ======== tile 0 ========
    PROLOGUE();
    asm volatile("s_waitcnt vmcnt(6)" ::: "memory");
    __builtin_amdgcn_s_barrier();
    KT_STEP(0, 0) KT_STEP(1, 0) KT_STEP(2, 0) KT_STEP(3, 0)
    KT_STEP(4, 0) KT_STEP(5, 0) KT_STEP(6, 0) KT_STEP(7, 0)

    // ======== inter-tile: issue tile-1 prologue loads, then (overlapped
    // VALU) margin+scale acc -> sv, rezero acc ========
    gBt += (size_t)128 * Dq;   // advance B staging to tile 1
    PROLOGUE();
    #pragma unroll
    for (int mi = 0; mi < 4; ++mi) {
        const int lab = labels[m0 + wr + mi * 16 + fr];
        #pragma unroll
        for (int ni = 0; ni < 4; ++ni) {
            const int gcol0 = n0 + wc + ni * 16 + kg * 4;
            f32x4 v = acc[mi][ni];
            #pragma unroll
            for (int r = 0; r < 4; ++r) {
                if (gcol0 + r == lab) {
                    float c = v[r];
                    float sine = sqrtf(fmaxf(1.0f - c * c, 0.0f));
                    float phi = c * COS_M - sine * SIN_M;
                    v[r] = (c > THR) ? phi : (c - MM);
                }
            }
            sv[mi][ni] = v * SCALE;
            acc[mi][ni] = {0.f, 0.f, 0.f, 0.f};
        }
    }
    asm volatile("s_waitcnt vmcnt(6)" ::: "memory");
    __builtin_amdgcn_s_barrier();

    // ======== tile 1 (tile-0 stores drip-fed 2/kt) ========
    KT_STEP(0, 1) KT_STEP(1, 1) KT_STEP(2, 1) KT_STEP(3, 1)
    KT_STEP(4, 1) KT_STEP(5, 1) KT_STEP(6, 1) KT_STEP(7, 1)

    // ---- tile-1 epilogue: acc -> LDS [128][132] f32 -> line-aligned nt
    // stores (2 rows x 512B per instruction). cols n0+128 .. n0+255.
    const int n0e = n0 + 128;
    float* lf = reinterpret_cast<float*>(lds);
    #pragma unroll
    for (int mi = 0; mi < 4; ++mi) {
        const int lrow = wr + mi * 16 + fr;
        const int lab = labels[m0 + lrow];
        #pragma unroll
        for (int ni = 0; ni < 4; ++ni) {
            const int col0 = wc + ni * 16 + kg * 4;
            const int gcol0 = n0e + col0;
            f32x4 v = acc[mi][ni];
            #pragma unroll
            for (int r = 0; r < 4; ++r) {
                if (gcol0 + r == lab) {
                    float c = v[r];
                    float sine = sqrtf(fmaxf(1.0f - c * c, 0.0f));
                    float phi = c * COS_M - sine * SIN_M;
                    v[r] = (c > THR) ? phi : (c - MM);
                }
            }
            v *= SCALE;
            *reinterpret_cast<f32x4*>(&lf[lrow * 132 + col0]) = v;
        }
    }
    __syncthreads();
    const int cc = lane & 31, rh = lane >> 5;
    #pragma unroll
    for (int s = 0; s < 16; ++s) {
        const int lrow = (w * 16 + s) * 2 + rh;
        f32x4 v = *reinterpret_cast<const f32x4*>(&lf[lrow * 132 + cc * 4]);
        const int gcol0 = n0e + cc * 4;
        if (gcol0 < Cq)
            __builtin_nontemporal_store(
                v, reinterpret_cast<f32x4*>(out + (size_t)(m0 + lrow) * Cq + gcol0));
    }
#undef STAGE_A
#undef STAGE_B
#undef BARRIER
#undef PROLOGUE
#undef LDAQ
#undef LDB
#undef MFMA_PAIR
#undef KT_STEP
}

extern "C" void kernel_launch(void* const* d_in, const int* in_sizes, int n_in,
                              void* d_out, int out_size, void* d_ws, size_t ws_size,
                              hipStream_t stream)
{
    const float* emb    = (const float*)d_in[0];
    const int*   labels = (const int*)d_in[1];
    const float* weight = (const float*)d_in[2];
    float* out = (float*)d_out;

    unsigned short* Abf = (unsigned short*)d_ws;             // 2 MB
    unsigned short* Bbf = Abf + (size_t)Bq * Dq;             // 102.5 MB

    normalize_rows_kernel<<<Bq / 4, 256, 0, stream>>>(emb, Abf, Bq);
    normalize_rows_kernel<<<NPAD / 4, 256, 0, stream>>>(weight, Bbf, Cq);
    arc_gemm_kernel<<<16 * (NPAD / 256), 256, 67584, stream>>>(Abf, Bbf, labels, out);
}